// Round 1
// baseline (336.754 us; speedup 1.0000x reference)
//
#include <hip/hip_runtime.h>

// Problem constants: B=2, S=2048, D_MODEL=1024, H=16, Dh=64, M = B*S = 4096.
// ws layout (bytes): Xb@0 (8M), Wqb@8M, Wkb@10M, Wvb@12M, Wob@14M (2M each),
// Q@16M, K@24M, V@32M, O@40M (8M each) -> 48 MB total.

typedef __attribute__((ext_vector_type(8))) short short8;
typedef __attribute__((ext_vector_type(4))) float f32x4;

__device__ __forceinline__ unsigned short f2bf(float f) {
  unsigned int x = __float_as_uint(f);
  x += 0x7fffu + ((x >> 16) & 1u);   // RNE
  return (unsigned short)(x >> 16);
}

__device__ __forceinline__ void gload16(const void* g, void* l) {
  // async global->LDS, 16B/lane; LDS dest must be wave-uniform base + lane*16
  __builtin_amdgcn_global_load_lds(
      (const __attribute__((address_space(1))) void*)g,
      (__attribute__((address_space(3))) void*)l, 16, 0, 0);
}

__global__ void cast_bf16_kernel(const float* __restrict__ in,
                                 unsigned short* __restrict__ out, int n4) {
  int i = blockIdx.x * blockDim.x + threadIdx.x;
  if (i >= n4) return;
  float4 v = ((const float4*)in)[i];
  union { unsigned short u[4]; uint2 p; } o;
  o.u[0] = f2bf(v.x); o.u[1] = f2bf(v.y); o.u[2] = f2bf(v.z); o.u[3] = f2bf(v.w);
  ((uint2*)out)[i] = o.p;
}

// ---------------- fused QKV projection: C = X @ W^T (both row-major over K) ----
#define GK 1024

__global__ __launch_bounds__(256) void gemm_qkv_kernel(
    const unsigned short* __restrict__ X,
    const unsigned short* __restrict__ Wq,
    const unsigned short* __restrict__ Wk,
    const unsigned short* __restrict__ Wv,
    unsigned short* __restrict__ Qo,
    unsigned short* __restrict__ Ko,
    unsigned short* __restrict__ Vo) {
  __shared__ unsigned short As[128 * 32];
  __shared__ unsigned short Bs[128 * 32];
  int mb = blockIdx.x;
  int nbT = blockIdx.y;
  int sel = nbT >> 3, nb = nbT & 7;
  const unsigned short* W = sel == 0 ? Wq : (sel == 1 ? Wk : Wv);
  unsigned short* C = sel == 0 ? Qo : (sel == 1 ? Ko : Vo);

  int tid = threadIdx.x;
  int w = tid >> 6, l = tid & 63, quad = l >> 4, lo = l & 15;
  int wm = (w >> 1) * 64, wn = (w & 1) * 64;

  f32x4 acc[4][4];
#pragma unroll
  for (int i = 0; i < 4; i++)
#pragma unroll
    for (int j = 0; j < 4; j++) acc[i][j] = (f32x4){0.f, 0.f, 0.f, 0.f};

  for (int k0 = 0; k0 < GK; k0 += 32) {
    __syncthreads();
#pragma unroll
    for (int i = 0; i < 2; i++) {
      int c = i * 256 + tid;  // 512 chunks of 16B per matrix; 4 chunks per row
      gload16(X + (size_t)(mb * 128 + (c >> 2)) * GK + k0 + (c & 3) * 8,
              (char*)As + c * 16);
      gload16(W + (size_t)(nb * 128 + (c >> 2)) * GK + k0 + (c & 3) * 8,
              (char*)Bs + c * 16);
    }
    __syncthreads();
    short8 a[4], b[4];
#pragma unroll
    for (int mi = 0; mi < 4; mi++)
      a[mi] = *(const short8*)&As[(wm + mi * 16 + lo) * 32 + quad * 8];
#pragma unroll
    for (int ni = 0; ni < 4; ni++)
      b[ni] = *(const short8*)&Bs[(wn + ni * 16 + lo) * 32 + quad * 8];
#pragma unroll
    for (int mi = 0; mi < 4; mi++)
#pragma unroll
      for (int ni = 0; ni < 4; ni++)
        acc[mi][ni] = __builtin_amdgcn_mfma_f32_16x16x32_bf16(a[mi], b[ni],
                                                              acc[mi][ni], 0, 0, 0);
  }
#pragma unroll
  for (int mi = 0; mi < 4; mi++)
#pragma unroll
    for (int ni = 0; ni < 4; ni++)
#pragma unroll
      for (int r = 0; r < 4; r++) {
        int row = mb * 128 + wm + mi * 16 + quad * 4 + r;
        int col = nb * 128 + wn + ni * 16 + lo;
        C[(size_t)row * 1024 + col] = f2bf(acc[mi][ni][r]);
      }
}

// ---------------- output projection: out(f32) = O @ Wo^T --------------------
__global__ __launch_bounds__(256) void gemm_out_kernel(
    const unsigned short* __restrict__ A,
    const unsigned short* __restrict__ W,
    float* __restrict__ C) {
  __shared__ unsigned short As[128 * 32];
  __shared__ unsigned short Bs[128 * 32];
  int mb = blockIdx.x, nb = blockIdx.y;
  int tid = threadIdx.x;
  int w = tid >> 6, l = tid & 63, quad = l >> 4, lo = l & 15;
  int wm = (w >> 1) * 64, wn = (w & 1) * 64;

  f32x4 acc[4][4];
#pragma unroll
  for (int i = 0; i < 4; i++)
#pragma unroll
    for (int j = 0; j < 4; j++) acc[i][j] = (f32x4){0.f, 0.f, 0.f, 0.f};

  for (int k0 = 0; k0 < GK; k0 += 32) {
    __syncthreads();
#pragma unroll
    for (int i = 0; i < 2; i++) {
      int c = i * 256 + tid;
      gload16(A + (size_t)(mb * 128 + (c >> 2)) * GK + k0 + (c & 3) * 8,
              (char*)As + c * 16);
      gload16(W + (size_t)(nb * 128 + (c >> 2)) * GK + k0 + (c & 3) * 8,
              (char*)Bs + c * 16);
    }
    __syncthreads();
    short8 a[4], b[4];
#pragma unroll
    for (int mi = 0; mi < 4; mi++)
      a[mi] = *(const short8*)&As[(wm + mi * 16 + lo) * 32 + quad * 8];
#pragma unroll
    for (int ni = 0; ni < 4; ni++)
      b[ni] = *(const short8*)&Bs[(wn + ni * 16 + lo) * 32 + quad * 8];
#pragma unroll
    for (int mi = 0; mi < 4; mi++)
#pragma unroll
      for (int ni = 0; ni < 4; ni++)
        acc[mi][ni] = __builtin_amdgcn_mfma_f32_16x16x32_bf16(a[mi], b[ni],
                                                              acc[mi][ni], 0, 0, 0);
  }
#pragma unroll
  for (int mi = 0; mi < 4; mi++)
#pragma unroll
    for (int ni = 0; ni < 4; ni++)
#pragma unroll
      for (int r = 0; r < 4; r++) {
        int row = mb * 128 + wm + mi * 16 + quad * 4 + r;
        int col = nb * 128 + wn + ni * 16 + lo;
        C[(size_t)row * 1024 + col] = acc[mi][ni][r];
      }
}

// ---------------- flash attention, causal; 1 block = (b,h, 64-row q tile) ----
__global__ __launch_bounds__(256) void attn_kernel(
    const unsigned short* __restrict__ Q,
    const unsigned short* __restrict__ K,
    const unsigned short* __restrict__ V,
    unsigned short* __restrict__ O) {
  const int S = 2048, DM = 1024;
  __shared__ unsigned short Qs[64 * 64], Ks[64 * 64], Vts[64 * 64];
  __shared__ unsigned short Ps[4][16 * 64];
  int qt = blockIdx.x, bh = blockIdx.y;
  int b = bh >> 4, h = bh & 15;
  size_t base = (size_t)b * S * DM + h * 64;
  int tid = threadIdx.x, w = tid >> 6, l = tid & 63, quad = l >> 4, lo = l & 15;

#pragma unroll
  for (int i = 0; i < 2; i++) {  // stage Q tile once: 64x64 bf16, 8 chunks/row
    int c = i * 256 + tid;
    gload16(Q + base + (size_t)(qt * 64 + (c >> 3)) * DM + (c & 7) * 8,
            (char*)Qs + c * 16);
  }

  float m_i[4], l_i[4];
  f32x4 oacc[4];
#pragma unroll
  for (int r = 0; r < 4; r++) { m_i[r] = -1e30f; l_i[r] = 0.f; }
#pragma unroll
  for (int ni = 0; ni < 4; ni++) oacc[ni] = (f32x4){0.f, 0.f, 0.f, 0.f};

  for (int t = 0; t <= qt; t++) {
    __syncthreads();  // prev iter reads done (also drains Q async at t=0)
#pragma unroll
    for (int i = 0; i < 2; i++) {
      int c = i * 256 + tid;
      gload16(K + base + (size_t)(t * 64 + (c >> 3)) * DM + (c & 7) * 8,
              (char*)Ks + c * 16);
    }
#pragma unroll
    for (int i = 0; i < 2; i++) {  // V transposed into LDS: Vts[d][kv]
      int d0 = (i * 4 + w) * 8;
      union { uint4 v; unsigned short u[8]; } pk;
      pk.v = *(const uint4*)(V + base + (size_t)(t * 64 + l) * DM + d0);
#pragma unroll
      for (int j = 0; j < 8; j++) Vts[(d0 + j) * 64 + l] = pk.u[j];
    }
    __syncthreads();

    // S-tile: wave w computes q-rows [w*16, w*16+16) x 64 kv cols
    f32x4 sacc[4];
#pragma unroll
    for (int ni = 0; ni < 4; ni++) sacc[ni] = (f32x4){0.f, 0.f, 0.f, 0.f};
#pragma unroll
    for (int ks = 0; ks < 2; ks++) {
      short8 aq = *(const short8*)&Qs[(w * 16 + lo) * 64 + ks * 32 + quad * 8];
#pragma unroll
      for (int ni = 0; ni < 4; ni++) {
        short8 bk = *(const short8*)&Ks[(ni * 16 + lo) * 64 + ks * 32 + quad * 8];
        sacc[ni] = __builtin_amdgcn_mfma_f32_16x16x32_bf16(aq, bk, sacc[ni], 0, 0, 0);
      }
    }

    float z[4][4];
#pragma unroll
    for (int ni = 0; ni < 4; ni++)
#pragma unroll
      for (int r = 0; r < 4; r++) {
        float v = sacc[ni][r] * 0.125f;  // 1/sqrt(64)
        if (t == qt) {
          int kvi = ni * 16 + lo, qi = w * 16 + quad * 4 + r;
          if (kvi > qi) v = -1e30f;
        }
        z[ni][r] = v;
      }

#pragma unroll
    for (int r = 0; r < 4; r++) {
      float mx = fmaxf(fmaxf(z[0][r], z[1][r]), fmaxf(z[2][r], z[3][r]));
      mx = fmaxf(mx, __shfl_xor(mx, 1));
      mx = fmaxf(mx, __shfl_xor(mx, 2));
      mx = fmaxf(mx, __shfl_xor(mx, 4));
      mx = fmaxf(mx, __shfl_xor(mx, 8));  // reduce across 16 lanes of quad
      float mnew = fmaxf(m_i[r], mx);
      float alpha = exp2f((m_i[r] - mnew) * 1.44269504f);
      m_i[r] = mnew;
      float rs = 0.f;
#pragma unroll
      for (int ni = 0; ni < 4; ni++) {
        float p = exp2f((z[ni][r] - mnew) * 1.44269504f);
        z[ni][r] = p;
        rs += p;
      }
      rs += __shfl_xor(rs, 1);
      rs += __shfl_xor(rs, 2);
      rs += __shfl_xor(rs, 4);
      rs += __shfl_xor(rs, 8);
      l_i[r] = l_i[r] * alpha + rs;
#pragma unroll
      for (int ni = 0; ni < 4; ni++) oacc[ni][r] *= alpha;
      // P (C-layout) -> LDS in A-operand order; own-wave region, DS in-order
#pragma unroll
      for (int ni = 0; ni < 4; ni++)
        Ps[w][(quad * 4 + r) * 64 + ni * 16 + lo] = f2bf(z[ni][r]);
    }

    // O += P @ V : A = P[16x64], B = V^T rows (d) contiguous over kv
#pragma unroll
    for (int ks = 0; ks < 2; ks++) {
      short8 ap = *(const short8*)&Ps[w][lo * 64 + ks * 32 + quad * 8];
#pragma unroll
      for (int ni = 0; ni < 4; ni++) {
        short8 bv = *(const short8*)&Vts[(ni * 16 + lo) * 64 + ks * 32 + quad * 8];
        oacc[ni] = __builtin_amdgcn_mfma_f32_16x16x32_bf16(ap, bv, oacc[ni], 0, 0, 0);
      }
    }
  }

#pragma unroll
  for (int ni = 0; ni < 4; ni++)
#pragma unroll
    for (int r = 0; r < 4; r++) {
      int row = qt * 64 + w * 16 + quad * 4 + r;
      int col = ni * 16 + lo;
      O[base + (size_t)row * DM + col] = f2bf(oacc[ni][r] / l_i[r]);
    }
}

extern "C" void kernel_launch(void* const* d_in, const int* in_sizes, int n_in,
                              void* d_out, int out_size, void* d_ws, size_t ws_size,
                              hipStream_t stream) {
  const float* x  = (const float*)d_in[0];
  const float* Wq = (const float*)d_in[1];
  const float* Wk = (const float*)d_in[2];
  const float* Wv = (const float*)d_in[3];
  const float* Wo = (const float*)d_in[4];
  float* out = (float*)d_out;
  char* ws = (char*)d_ws;

  unsigned short* Xb  = (unsigned short*)(ws);
  unsigned short* Wqb = (unsigned short*)(ws + (8ll  << 20));
  unsigned short* Wkb = (unsigned short*)(ws + (10ll << 20));
  unsigned short* Wvb = (unsigned short*)(ws + (12ll << 20));
  unsigned short* Wob = (unsigned short*)(ws + (14ll << 20));
  unsigned short* Qb  = (unsigned short*)(ws + (16ll << 20));
  unsigned short* Kb  = (unsigned short*)(ws + (24ll << 20));
  unsigned short* Vb  = (unsigned short*)(ws + (32ll << 20));
  unsigned short* Ob  = (unsigned short*)(ws + (40ll << 20));

  // casts to bf16
  cast_bf16_kernel<<<4096, 256, 0, stream>>>(x, Xb, 4194304 / 4);
  cast_bf16_kernel<<<1024, 256, 0, stream>>>(Wq, Wqb, 1048576 / 4);
  cast_bf16_kernel<<<1024, 256, 0, stream>>>(Wk, Wkb, 1048576 / 4);
  cast_bf16_kernel<<<1024, 256, 0, stream>>>(Wv, Wvb, 1048576 / 4);
  cast_bf16_kernel<<<1024, 256, 0, stream>>>(Wo, Wob, 1048576 / 4);

  // fused QKV projection: M=4096 (32 blocks) x N=3*1024 (24 blocks)
  gemm_qkv_kernel<<<dim3(32, 24), 256, 0, stream>>>(Xb, Wqb, Wkb, Wvb, Qb, Kb, Vb);

  // causal flash attention: 32 q-tiles x 32 (b,h)
  attn_kernel<<<dim3(32, 32), 256, 0, stream>>>(Qb, Kb, Vb, Ob);

  // output projection -> fp32
  gemm_out_kernel<<<dim3(32, 8), 256, 0, stream>>>(Ob, Wob, out);
}

// Round 2
// 215.928 us; speedup vs baseline: 1.5596x; 1.5596x over previous
//
#include <hip/hip_runtime.h>

// B=2, S=2048, D_MODEL=1024, H=16, Dh=64, M=B*S=4096.
// ws: Xb@0(8M) Wqb@8M Wkb@10M Wvb@12M Wob@14M (2M each, bf16)
//     Qb@16M(8M,bf16,pre-scaled by 1/8*log2e) Kb@24M(8M,bf16)
//     Vt@32M(8M,f16, layout [bh*64+d][2048]) Ob@40M(8M,bf16)

typedef __attribute__((ext_vector_type(8))) short short8;
typedef __attribute__((ext_vector_type(4))) float f32x4;
typedef __attribute__((ext_vector_type(4))) _Float16 half4;

#if __has_builtin(__builtin_amdgcn_exp2f)
#define EXP2F(x) __builtin_amdgcn_exp2f(x)
#else
#define EXP2F(x) exp2f(x)
#endif

__device__ __forceinline__ unsigned short f2bf(float f) {
  unsigned int x = __float_as_uint(f);
  x += 0x7fffu + ((x >> 16) & 1u);  // RNE
  return (unsigned short)(x >> 16);
}

__device__ __forceinline__ void gload16(const void* g, void* l) {
  __builtin_amdgcn_global_load_lds(
      (const __attribute__((address_space(1))) void*)g,
      (__attribute__((address_space(3))) void*)l, 16, 0, 0);
}

// swizzled LDS offset (in 2-byte units) for 64-element rows:
// physical 16B chunk = logical chunk ^ (row & 7)
__device__ __forceinline__ int swz64(int row, int sc) {
  return row * 64 + ((((sc >> 3) ^ (row & 7)) << 3) | (sc & 7));
}

// ---------------- fused cast (x, Wq*scale, Wk, Wv, Wo) ----------------------
__global__ void cast5_kernel(const float* __restrict__ x, const float* __restrict__ wq,
                             const float* __restrict__ wk, const float* __restrict__ wv,
                             const float* __restrict__ wo,
                             unsigned short* __restrict__ xb, unsigned short* __restrict__ wqb,
                             unsigned short* __restrict__ wkb, unsigned short* __restrict__ wvb,
                             unsigned short* __restrict__ wob) {
  const float* in; unsigned short* out; int n4; float sc = 1.f;
  switch (blockIdx.y) {
    case 0: in = x;  out = xb;  n4 = 1048576; break;
    case 1: in = wq; out = wqb; n4 = 262144; sc = 0.18033688011112042f; break;  // (1/8)*log2(e)
    case 2: in = wk; out = wkb; n4 = 262144; break;
    case 3: in = wv; out = wvb; n4 = 262144; break;
    default: in = wo; out = wob; n4 = 262144; break;
  }
  int i = blockIdx.x * 256 + threadIdx.x;
  if (i >= n4) return;
  float4 v = ((const float4*)in)[i];
  union { unsigned short u[4]; uint2 p; } o;
  o.u[0] = f2bf(v.x * sc); o.u[1] = f2bf(v.y * sc);
  o.u[2] = f2bf(v.z * sc); o.u[3] = f2bf(v.w * sc);
  ((uint2*)out)[i] = o.p;
}

// ---------------- fused QKV projection: C = X @ W^T; V written transposed ----
#define GK 1024

__global__ __launch_bounds__(256) void gemm_qkv_kernel(
    const unsigned short* __restrict__ X,
    const unsigned short* __restrict__ Wq,
    const unsigned short* __restrict__ Wk,
    const unsigned short* __restrict__ Wv,
    unsigned short* __restrict__ Qo,
    unsigned short* __restrict__ Ko,
    _Float16* __restrict__ Vt) {
  __shared__ unsigned short As[128 * 32];
  __shared__ unsigned short Bs[128 * 32];
  int mb = blockIdx.x;
  int nbT = blockIdx.y;
  int sel = nbT >> 3, nb = nbT & 7;
  const unsigned short* W = sel == 0 ? Wq : (sel == 1 ? Wk : Wv);

  int tid = threadIdx.x;
  int w = tid >> 6, l = tid & 63, quad = l >> 4, lo = l & 15;
  int wm = (w >> 1) * 64, wn = (w & 1) * 64;

  f32x4 acc[4][4];
#pragma unroll
  for (int i = 0; i < 4; i++)
#pragma unroll
    for (int j = 0; j < 4; j++) acc[i][j] = (f32x4){0.f, 0.f, 0.f, 0.f};

  for (int k0 = 0; k0 < GK; k0 += 32) {
    __syncthreads();
#pragma unroll
    for (int i = 0; i < 2; i++) {
      int c = i * 256 + tid;
      gload16(X + (size_t)(mb * 128 + (c >> 2)) * GK + k0 + (c & 3) * 8,
              (char*)As + c * 16);
      gload16(W + (size_t)(nb * 128 + (c >> 2)) * GK + k0 + (c & 3) * 8,
              (char*)Bs + c * 16);
    }
    __syncthreads();
    short8 a[4], b[4];
#pragma unroll
    for (int mi = 0; mi < 4; mi++)
      a[mi] = *(const short8*)&As[(wm + mi * 16 + lo) * 32 + quad * 8];
#pragma unroll
    for (int ni = 0; ni < 4; ni++)
      b[ni] = *(const short8*)&Bs[(wn + ni * 16 + lo) * 32 + quad * 8];
#pragma unroll
    for (int mi = 0; mi < 4; mi++)
#pragma unroll
      for (int ni = 0; ni < 4; ni++)
        acc[mi][ni] = __builtin_amdgcn_mfma_f32_16x16x32_bf16(a[mi], b[ni],
                                                              acc[mi][ni], 0, 0, 0);
  }
  if (sel == 2) {
    // V^T epilogue: Vt[(b*16+h)*64 + d][s], f16, 8B store of 4 consecutive s
#pragma unroll
    for (int mi = 0; mi < 4; mi++)
#pragma unroll
      for (int ni = 0; ni < 4; ni++) {
        int row0 = mb * 128 + wm + mi * 16 + quad * 4;
        int col = nb * 128 + wn + ni * 16 + lo;
        int bb = row0 >> 11, ss = row0 & 2047;
        int hh = col >> 6, dd = col & 63;
        half4 v;
#pragma unroll
        for (int r = 0; r < 4; r++) v[r] = (_Float16)acc[mi][ni][r];
        *(half4*)&Vt[((size_t)((bb * 16 + hh) * 64 + dd)) * 2048 + ss] = v;
      }
  } else {
    unsigned short* C = sel == 0 ? Qo : Ko;
#pragma unroll
    for (int mi = 0; mi < 4; mi++)
#pragma unroll
      for (int ni = 0; ni < 4; ni++)
#pragma unroll
        for (int r = 0; r < 4; r++) {
          int row = mb * 128 + wm + mi * 16 + quad * 4 + r;
          int col = nb * 128 + wn + ni * 16 + lo;
          C[(size_t)row * 1024 + col] = f2bf(acc[mi][ni][r]);
        }
  }
}

// ---------------- output projection: out(f32) = O @ Wo^T --------------------
__global__ __launch_bounds__(256) void gemm_out_kernel(
    const unsigned short* __restrict__ A,
    const unsigned short* __restrict__ W,
    float* __restrict__ C) {
  __shared__ unsigned short As[128 * 32];
  __shared__ unsigned short Bs[128 * 32];
  int mb = blockIdx.x, nb = blockIdx.y;
  int tid = threadIdx.x;
  int w = tid >> 6, l = tid & 63, quad = l >> 4, lo = l & 15;
  int wm = (w >> 1) * 64, wn = (w & 1) * 64;

  f32x4 acc[4][4];
#pragma unroll
  for (int i = 0; i < 4; i++)
#pragma unroll
    for (int j = 0; j < 4; j++) acc[i][j] = (f32x4){0.f, 0.f, 0.f, 0.f};

  for (int k0 = 0; k0 < GK; k0 += 32) {
    __syncthreads();
#pragma unroll
    for (int i = 0; i < 2; i++) {
      int c = i * 256 + tid;
      gload16(A + (size_t)(mb * 128 + (c >> 2)) * GK + k0 + (c & 3) * 8,
              (char*)As + c * 16);
      gload16(W + (size_t)(nb * 128 + (c >> 2)) * GK + k0 + (c & 3) * 8,
              (char*)Bs + c * 16);
    }
    __syncthreads();
    short8 a[4], b[4];
#pragma unroll
    for (int mi = 0; mi < 4; mi++)
      a[mi] = *(const short8*)&As[(wm + mi * 16 + lo) * 32 + quad * 8];
#pragma unroll
    for (int ni = 0; ni < 4; ni++)
      b[ni] = *(const short8*)&Bs[(wn + ni * 16 + lo) * 32 + quad * 8];
#pragma unroll
    for (int mi = 0; mi < 4; mi++)
#pragma unroll
      for (int ni = 0; ni < 4; ni++)
        acc[mi][ni] = __builtin_amdgcn_mfma_f32_16x16x32_bf16(a[mi], b[ni],
                                                              acc[mi][ni], 0, 0, 0);
  }
#pragma unroll
  for (int mi = 0; mi < 4; mi++)
#pragma unroll
    for (int ni = 0; ni < 4; ni++)
#pragma unroll
      for (int r = 0; r < 4; r++) {
        int row = mb * 128 + wm + mi * 16 + quad * 4 + r;
        int col = nb * 128 + wn + ni * 16 + lo;
        C[(size_t)row * 1024 + col] = acc[mi][ni][r];
      }
}

// ---------------- flash attention, causal; block = (qt 128 rows, b, h) ------
// S^T via 16x16x32 bf16 (A=K, B=Q) -> C-layout == A-fragment layout of
// 16x16x16 f16 PV MFMA: P stays in registers. Softmax rows are lane-indexed.
__global__ __launch_bounds__(256) void attn_kernel(
    const unsigned short* __restrict__ Q,
    const unsigned short* __restrict__ K,
    const _Float16* __restrict__ Vt,
    unsigned short* __restrict__ O) {
  const int S = 2048, DM = 1024;
  __shared__ unsigned short Qs[128 * 64];
  __shared__ unsigned short Ks[64 * 64];
  __shared__ _Float16 Vts[64 * 64];

  int id = blockIdx.x;
  int qidx = id >> 5, bh = id & 31;
  int qt = (qidx < 8) ? qidx : 23 - qidx;  // pair qt with 15-qt per CU (balance)
  int b = bh >> 4, h = bh & 15;
  size_t base = (size_t)b * S * DM + h * 64;
  size_t baseVt = (size_t)(bh * 64) * S;

  int tid = threadIdx.x;
  int w = tid >> 6, lane = tid & 63, quad = lane >> 4, lo = lane & 15;
  int qb_w = qt * 128 + w * 32;  // wave's first q row

  // stage Q tile once (swizzled)
#pragma unroll
  for (int j = 0; j < 4; j++) {
    int s_ = j * 256 + tid;
    int row = s_ >> 3, lc = (s_ & 7) ^ (row & 7);
    gload16(Q + base + (size_t)(qt * 128 + row) * DM + lc * 8, (char*)Qs + s_ * 16);
  }

  short8 qf[2][2];
  f32x4 oacc[2][4];
  float m_[2], l_[2];
#pragma unroll
  for (int s = 0; s < 2; s++) {
    m_[s] = -1e30f; l_[s] = 0.f;
#pragma unroll
    for (int ni = 0; ni < 4; ni++) oacc[s][ni] = (f32x4){0.f, 0.f, 0.f, 0.f};
  }

  int tend = 2 * qt + 2;
  for (int t = 0; t < tend; t++) {
    __syncthreads();  // prev-iter reads done; at t=0 also drains Q staging
#pragma unroll
    for (int j = 0; j < 2; j++) {
      int s_ = j * 256 + tid;
      int row = s_ >> 3, lc = (s_ & 7) ^ (row & 7);
      gload16(K + base + (size_t)(t * 64 + row) * DM + lc * 8, (char*)Ks + s_ * 16);
      gload16(Vt + baseVt + (size_t)row * S + t * 64 + lc * 8, (char*)Vts + s_ * 16);
    }
    if (t == 0) {  // Qs valid after first barrier; cache fragments in registers
#pragma unroll
      for (int s = 0; s < 2; s++)
#pragma unroll
        for (int d = 0; d < 2; d++)
          qf[s][d] = *(const short8*)&Qs[swz64(w * 32 + s * 16 + lo, d * 32 + quad * 8)];
    }
    __syncthreads();

    // S^T[kv][q] per kvt tile; Q pre-scaled so values are log2-domain scores
    f32x4 st[2][4];
#pragma unroll
    for (int s = 0; s < 2; s++)
#pragma unroll
      for (int kvt = 0; kvt < 4; kvt++) st[s][kvt] = (f32x4){0.f, 0.f, 0.f, 0.f};
#pragma unroll
    for (int kvt = 0; kvt < 4; kvt++)
#pragma unroll
      for (int d = 0; d < 2; d++) {
        short8 kf = *(const short8*)&Ks[swz64(kvt * 16 + lo, d * 32 + quad * 8)];
        st[0][kvt] = __builtin_amdgcn_mfma_f32_16x16x32_bf16(kf, qf[0][d], st[0][kvt], 0, 0, 0);
        st[1][kvt] = __builtin_amdgcn_mfma_f32_16x16x32_bf16(kf, qf[1][d], st[1][kvt], 0, 0, 0);
      }

    half4 pf[2][4];
#pragma unroll
    for (int s = 0; s < 2; s++) {
      int qrow0 = qb_w + s * 16;
      float z[4][4];
#pragma unroll
      for (int kvt = 0; kvt < 4; kvt++)
#pragma unroll
        for (int r = 0; r < 4; r++) z[kvt][r] = st[s][kvt][r];
      if (t * 64 + 63 > qrow0) {  // wave-uniform causal-boundary guard
        int qg = qrow0 + lo;
#pragma unroll
        for (int kvt = 0; kvt < 4; kvt++)
#pragma unroll
          for (int r = 0; r < 4; r++) {
            int kv = t * 64 + kvt * 16 + quad * 4 + r;
            if (kv > qg) z[kvt][r] = -1e30f;
          }
      }
      float mx = z[0][0];
#pragma unroll
      for (int kvt = 0; kvt < 4; kvt++)
#pragma unroll
        for (int r = 0; r < 4; r++) mx = fmaxf(mx, z[kvt][r]);
      mx = fmaxf(mx, __shfl_xor(mx, 16));
      mx = fmaxf(mx, __shfl_xor(mx, 32));  // row q=lo fully reduced, all quads
      float mnew = fmaxf(m_[s], mx);
      float alpha = EXP2F(m_[s] - mnew);
      m_[s] = mnew;
      float rs = 0.f;
#pragma unroll
      for (int kvt = 0; kvt < 4; kvt++)
#pragma unroll
        for (int r = 0; r < 4; r++) {
          float p = EXP2F(z[kvt][r] - mnew);
          z[kvt][r] = p;
          rs += p;
        }
      rs += __shfl_xor(rs, 16);
      rs += __shfl_xor(rs, 32);
      l_[s] = l_[s] * alpha + rs;
#pragma unroll
      for (int kvt = 0; kvt < 4; kvt++) {
        half4 p4;
#pragma unroll
        for (int r = 0; r < 4; r++) p4[r] = (_Float16)z[kvt][r];
        pf[s][kvt] = p4;
      }
      // alpha lives at q=lo layout; oacc rows are q=quad*4+r -> broadcast
      float ab[4];
#pragma unroll
      for (int r = 0; r < 4; r++) ab[r] = __shfl(alpha, (lane & 48) + quad * 4 + r);
#pragma unroll
      for (int ni = 0; ni < 4; ni++)
#pragma unroll
        for (int r = 0; r < 4; r++) oacc[s][ni][r] *= ab[r];
    }

    // O += P @ V, K=16 f16 MFMA; P a-frags already in registers
#pragma unroll
    for (int kvt = 0; kvt < 4; kvt++) {
      half4 vf[4];
#pragma unroll
      for (int ni = 0; ni < 4; ni++)
        vf[ni] = *(const half4*)&Vts[swz64(ni * 16 + lo, kvt * 16 + quad * 4)];
#pragma unroll
      for (int s = 0; s < 2; s++)
#pragma unroll
        for (int ni = 0; ni < 4; ni++)
          oacc[s][ni] = __builtin_amdgcn_mfma_f32_16x16x16f16(pf[s][kvt], vf[ni],
                                                              oacc[s][ni], 0, 0, 0);
    }
  }

#pragma unroll
  for (int s = 0; s < 2; s++) {
    float inv[4];
#pragma unroll
    for (int r = 0; r < 4; r++)
      inv[r] = 1.0f / __shfl(l_[s], (lane & 48) + quad * 4 + r);
#pragma unroll
    for (int ni = 0; ni < 4; ni++)
#pragma unroll
      for (int r = 0; r < 4; r++) {
        int qg = qb_w + s * 16 + quad * 4 + r;
        O[base + (size_t)qg * DM + ni * 16 + lo] = f2bf(oacc[s][ni][r] * inv[r]);
      }
  }
}

extern "C" void kernel_launch(void* const* d_in, const int* in_sizes, int n_in,
                              void* d_out, int out_size, void* d_ws, size_t ws_size,
                              hipStream_t stream) {
  const float* x  = (const float*)d_in[0];
  const float* Wq = (const float*)d_in[1];
  const float* Wk = (const float*)d_in[2];
  const float* Wv = (const float*)d_in[3];
  const float* Wo = (const float*)d_in[4];
  float* out = (float*)d_out;
  char* ws = (char*)d_ws;

  unsigned short* Xb  = (unsigned short*)(ws);
  unsigned short* Wqb = (unsigned short*)(ws + (8ll  << 20));
  unsigned short* Wkb = (unsigned short*)(ws + (10ll << 20));
  unsigned short* Wvb = (unsigned short*)(ws + (12ll << 20));
  unsigned short* Wob = (unsigned short*)(ws + (14ll << 20));
  unsigned short* Qb  = (unsigned short*)(ws + (16ll << 20));
  unsigned short* Kb  = (unsigned short*)(ws + (24ll << 20));
  _Float16*       Vt  = (_Float16*)     (ws + (32ll << 20));
  unsigned short* Ob  = (unsigned short*)(ws + (40ll << 20));

  cast5_kernel<<<dim3(4096, 5), 256, 0, stream>>>(x, Wq, Wk, Wv, Wo,
                                                  Xb, Wqb, Wkb, Wvb, Wob);
  gemm_qkv_kernel<<<dim3(32, 24), 256, 0, stream>>>(Xb, Wqb, Wkb, Wvb, Qb, Kb, Vt);
  attn_kernel<<<512, 256, 0, stream>>>(Qb, Kb, Vt, Ob);
  gemm_out_kernel<<<dim3(32, 8), 256, 0, stream>>>(Ob, Wob, out);
}

// Round 3
// 193.194 us; speedup vs baseline: 1.7431x; 1.1177x over previous
//
#include <hip/hip_runtime.h>

// B=2, S=2048, D_MODEL=1024, H=16, Dh=64, M=B*S=4096.
// ws: Xb@0(8M) Wqb@8M Wkb@10M Wvb@12M Wob@14M (2M each, bf16)
//     Qb@16M(8M,bf16,pre-scaled by 1/8*log2e) Kb@24M(8M,bf16)
//     Vt@32M(8M,f16, layout [bh*64+d][2048]) Ob@40M(8M,bf16)

typedef __attribute__((ext_vector_type(8))) short short8;
typedef __attribute__((ext_vector_type(4))) float f32x4;
typedef __attribute__((ext_vector_type(4))) _Float16 half4;

#if __has_builtin(__builtin_amdgcn_exp2f)
#define EXP2F(x) __builtin_amdgcn_exp2f(x)
#else
#define EXP2F(x) exp2f(x)
#endif

__device__ __forceinline__ unsigned short f2bf(float f) {
  unsigned int x = __float_as_uint(f);
  x += 0x7fffu + ((x >> 16) & 1u);  // RNE
  return (unsigned short)(x >> 16);
}

__device__ __forceinline__ void gload16(const void* g, void* l) {
  __builtin_amdgcn_global_load_lds(
      (const __attribute__((address_space(1))) void*)g,
      (__attribute__((address_space(3))) void*)l, 16, 0, 0);
}

// swizzled LDS offset (2-byte units) for 64-element rows:
// physical 16B chunk = logical chunk ^ (row & 7)
__device__ __forceinline__ int swz64(int row, int sc) {
  return row * 64 + ((((sc >> 3) ^ (row & 7)) << 3) | (sc & 7));
}

// ---------------- fused cast (x, Wq*scale, Wk, Wv, Wo) ----------------------
__global__ void cast5_kernel(const float* __restrict__ x, const float* __restrict__ wq,
                             const float* __restrict__ wk, const float* __restrict__ wv,
                             const float* __restrict__ wo,
                             unsigned short* __restrict__ xb, unsigned short* __restrict__ wqb,
                             unsigned short* __restrict__ wkb, unsigned short* __restrict__ wvb,
                             unsigned short* __restrict__ wob) {
  const float* in; unsigned short* out; int n4; float sc = 1.f;
  switch (blockIdx.y) {
    case 0: in = x;  out = xb;  n4 = 1048576; break;
    case 1: in = wq; out = wqb; n4 = 262144; sc = 0.18033688011112042f; break;  // (1/8)*log2(e)
    case 2: in = wk; out = wkb; n4 = 262144; break;
    case 3: in = wv; out = wvb; n4 = 262144; break;
    default: in = wo; out = wob; n4 = 262144; break;
  }
  int i = blockIdx.x * 256 + threadIdx.x;
  if (i >= n4) return;
  float4 v = ((const float4*)in)[i];
  union { unsigned short u[4]; uint2 p; } o;
  o.u[0] = f2bf(v.x * sc); o.u[1] = f2bf(v.y * sc);
  o.u[2] = f2bf(v.z * sc); o.u[3] = f2bf(v.w * sc);
  ((uint2*)out)[i] = o.p;
}

// ---------------- fused QKV projection: C = X @ W^T; V written transposed ----
#define GK 1024

__global__ __launch_bounds__(256) void gemm_qkv_kernel(
    const unsigned short* __restrict__ X,
    const unsigned short* __restrict__ Wq,
    const unsigned short* __restrict__ Wk,
    const unsigned short* __restrict__ Wv,
    unsigned short* __restrict__ Qo,
    unsigned short* __restrict__ Ko,
    _Float16* __restrict__ Vt) {
  __shared__ unsigned short As[128 * 32];
  __shared__ unsigned short Bs[128 * 32];
  int mb = blockIdx.x;
  int nbT = blockIdx.y;
  int sel = nbT >> 3, nb = nbT & 7;
  const unsigned short* W = sel == 0 ? Wq : (sel == 1 ? Wk : Wv);

  int tid = threadIdx.x;
  int w = tid >> 6, l = tid & 63, quad = l >> 4, lo = l & 15;
  int wm = (w >> 1) * 64, wn = (w & 1) * 64;

  f32x4 acc[4][4];
#pragma unroll
  for (int i = 0; i < 4; i++)
#pragma unroll
    for (int j = 0; j < 4; j++) acc[i][j] = (f32x4){0.f, 0.f, 0.f, 0.f};

  for (int k0 = 0; k0 < GK; k0 += 32) {
    __syncthreads();
#pragma unroll
    for (int i = 0; i < 2; i++) {
      int c = i * 256 + tid;
      gload16(X + (size_t)(mb * 128 + (c >> 2)) * GK + k0 + (c & 3) * 8,
              (char*)As + c * 16);
      gload16(W + (size_t)(nb * 128 + (c >> 2)) * GK + k0 + (c & 3) * 8,
              (char*)Bs + c * 16);
    }
    __syncthreads();
    short8 a[4], b[4];
#pragma unroll
    for (int mi = 0; mi < 4; mi++)
      a[mi] = *(const short8*)&As[(wm + mi * 16 + lo) * 32 + quad * 8];
#pragma unroll
    for (int ni = 0; ni < 4; ni++)
      b[ni] = *(const short8*)&Bs[(wn + ni * 16 + lo) * 32 + quad * 8];
#pragma unroll
    for (int mi = 0; mi < 4; mi++)
#pragma unroll
      for (int ni = 0; ni < 4; ni++)
        acc[mi][ni] = __builtin_amdgcn_mfma_f32_16x16x32_bf16(a[mi], b[ni],
                                                              acc[mi][ni], 0, 0, 0);
  }
  if (sel == 2) {
    // V^T epilogue: Vt[(b*16+h)*64 + d][s], f16, 8B store of 4 consecutive s
#pragma unroll
    for (int mi = 0; mi < 4; mi++)
#pragma unroll
      for (int ni = 0; ni < 4; ni++) {
        int row0 = mb * 128 + wm + mi * 16 + quad * 4;
        int col = nb * 128 + wn + ni * 16 + lo;
        int bb = row0 >> 11, ss = row0 & 2047;
        int hh = col >> 6, dd = col & 63;
        half4 v;
#pragma unroll
        for (int r = 0; r < 4; r++) v[r] = (_Float16)acc[mi][ni][r];
        *(half4*)&Vt[((size_t)((bb * 16 + hh) * 64 + dd)) * 2048 + ss] = v;
      }
  } else {
    unsigned short* C = sel == 0 ? Qo : Ko;
#pragma unroll
    for (int mi = 0; mi < 4; mi++)
#pragma unroll
      for (int ni = 0; ni < 4; ni++)
#pragma unroll
        for (int r = 0; r < 4; r++) {
          int row = mb * 128 + wm + mi * 16 + quad * 4 + r;
          int col = nb * 128 + wn + ni * 16 + lo;
          C[(size_t)row * 1024 + col] = f2bf(acc[mi][ni][r]);
        }
  }
}

// ---------------- output projection: out(f32) = O @ Wo^T, 128x64 tiles ------
__global__ __launch_bounds__(256) void gemm_out_kernel(
    const unsigned short* __restrict__ A,
    const unsigned short* __restrict__ W,
    float* __restrict__ C) {
  __shared__ unsigned short As[128 * 32];
  __shared__ unsigned short Bs[64 * 32];
  int mb = blockIdx.x, nb = blockIdx.y;
  int tid = threadIdx.x;
  int w = tid >> 6, l = tid & 63, quad = l >> 4, lo = l & 15;
  int wm = w * 32;

  f32x4 acc[2][4];
#pragma unroll
  for (int i = 0; i < 2; i++)
#pragma unroll
    for (int j = 0; j < 4; j++) acc[i][j] = (f32x4){0.f, 0.f, 0.f, 0.f};

  for (int k0 = 0; k0 < GK; k0 += 32) {
    __syncthreads();
#pragma unroll
    for (int i = 0; i < 2; i++) {
      int c = i * 256 + tid;
      gload16(A + (size_t)(mb * 128 + (c >> 2)) * GK + k0 + (c & 3) * 8,
              (char*)As + c * 16);
    }
    gload16(W + (size_t)(nb * 64 + (tid >> 2)) * GK + k0 + (tid & 3) * 8,
            (char*)Bs + tid * 16);
    __syncthreads();
    short8 a[2], b[4];
#pragma unroll
    for (int mi = 0; mi < 2; mi++)
      a[mi] = *(const short8*)&As[(wm + mi * 16 + lo) * 32 + quad * 8];
#pragma unroll
    for (int ni = 0; ni < 4; ni++)
      b[ni] = *(const short8*)&Bs[(ni * 16 + lo) * 32 + quad * 8];
#pragma unroll
    for (int mi = 0; mi < 2; mi++)
#pragma unroll
      for (int ni = 0; ni < 4; ni++)
        acc[mi][ni] = __builtin_amdgcn_mfma_f32_16x16x32_bf16(a[mi], b[ni],
                                                              acc[mi][ni], 0, 0, 0);
  }
#pragma unroll
  for (int mi = 0; mi < 2; mi++)
#pragma unroll
    for (int ni = 0; ni < 4; ni++)
#pragma unroll
      for (int r = 0; r < 4; r++) {
        int row = mb * 128 + wm + mi * 16 + quad * 4 + r;
        int col = nb * 64 + ni * 16 + lo;
        C[(size_t)row * 1024 + col] = acc[mi][ni][r];
      }
}

// ---------------- flash attention, causal; block = (qt 64 rows, b, h) -------
// S^T via 16x16x32 bf16 (A=K, B=Q); P stays in registers (C-layout == A-frag
// of 16x16x16 f16). Single-barrier double-buffered K/V pipeline.
__global__ __launch_bounds__(256) void attn_kernel(
    const unsigned short* __restrict__ Q,
    const unsigned short* __restrict__ K,
    const _Float16* __restrict__ Vt,
    unsigned short* __restrict__ O) {
  const int S = 2048, DM = 1024;
  __shared__ unsigned short Qs[64 * 64];
  __shared__ unsigned short Ks[2][64 * 64];
  __shared__ _Float16 Vts[2][64 * 64];

  int id = blockIdx.x;
  int bh = id & 31;
  int qt = 31 - (id >> 5);  // longest blocks dispatch first (tail backfill)
  int b = bh >> 4, h = bh & 15;
  size_t base = (size_t)b * S * DM + h * 64;
  size_t baseVt = (size_t)(bh * 64) * S;

  int tid = threadIdx.x;
  int w = tid >> 6, lane = tid & 63, quad = lane >> 4, lo = lane & 15;
  int qrow0 = qt * 64 + w * 16;  // wave's first q row

  // prologue: stage Q tile + K/V tile 0 into buf 0 (all swizzled)
#pragma unroll
  for (int j = 0; j < 2; j++) {
    int s_ = j * 256 + tid;
    int row = s_ >> 3, lc = (s_ & 7) ^ (row & 7);
    gload16(Q + base + (size_t)(qt * 64 + row) * DM + lc * 8, (char*)Qs + s_ * 16);
  }
#pragma unroll
  for (int j = 0; j < 2; j++) {
    int s_ = j * 256 + tid;
    int row = s_ >> 3, lc = (s_ & 7) ^ (row & 7);
    gload16(K + base + (size_t)row * DM + lc * 8, (char*)Ks[0] + s_ * 16);
    gload16(Vt + baseVt + (size_t)row * S + lc * 8, (char*)Vts[0] + s_ * 16);
  }

  short8 qf[2];
  f32x4 oacc[4];
  float m_ = -1e30f, l_ = 0.f;
#pragma unroll
  for (int ni = 0; ni < 4; ni++) oacc[ni] = (f32x4){0.f, 0.f, 0.f, 0.f};

  int tend = qt + 1;
  for (int t = 0; t < tend; t++) {
    // barrier drains vmcnt -> buf[t&1] (and Qs at t=0) ready for all waves;
    // also separates iter t-1's readers of buf[(t+1)&1] from the prefetch below
    __syncthreads();
    if (t + 1 < tend) {
      int tb = (t + 1) & 1;
#pragma unroll
      for (int j = 0; j < 2; j++) {
        int s_ = j * 256 + tid;
        int row = s_ >> 3, lc = (s_ & 7) ^ (row & 7);
        gload16(K + base + (size_t)((t + 1) * 64 + row) * DM + lc * 8,
                (char*)Ks[tb] + s_ * 16);
        gload16(Vt + baseVt + (size_t)row * S + (t + 1) * 64 + lc * 8,
                (char*)Vts[tb] + s_ * 16);
      }
    }
    if (t == 0) {  // cache Q fragments in registers
#pragma unroll
      for (int d = 0; d < 2; d++)
        qf[d] = *(const short8*)&Qs[swz64(w * 16 + lo, d * 32 + quad * 8)];
    }
    const unsigned short* ks = Ks[t & 1];
    const _Float16* vs = Vts[t & 1];

    // S^T[kv][q]; Q pre-scaled -> log2-domain scores
    f32x4 st[4];
#pragma unroll
    for (int kvt = 0; kvt < 4; kvt++) st[kvt] = (f32x4){0.f, 0.f, 0.f, 0.f};
#pragma unroll
    for (int kvt = 0; kvt < 4; kvt++)
#pragma unroll
      for (int d = 0; d < 2; d++) {
        short8 kf = *(const short8*)&ks[swz64(kvt * 16 + lo, d * 32 + quad * 8)];
        st[kvt] = __builtin_amdgcn_mfma_f32_16x16x32_bf16(kf, qf[d], st[kvt], 0, 0, 0);
      }

    float z[4][4];
#pragma unroll
    for (int kvt = 0; kvt < 4; kvt++)
#pragma unroll
      for (int r = 0; r < 4; r++) z[kvt][r] = st[kvt][r];
    if (t == tend - 1) {  // diagonal tile: causal mask
      int qg = qrow0 + lo;
#pragma unroll
      for (int kvt = 0; kvt < 4; kvt++)
#pragma unroll
        for (int r = 0; r < 4; r++) {
          int kv = t * 64 + kvt * 16 + quad * 4 + r;
          if (kv > qg) z[kvt][r] = -1e30f;
        }
    }

    float mx = z[0][0];
#pragma unroll
    for (int kvt = 0; kvt < 4; kvt++)
#pragma unroll
      for (int r = 0; r < 4; r++) mx = fmaxf(mx, z[kvt][r]);
    mx = fmaxf(mx, __shfl_xor(mx, 16));
    mx = fmaxf(mx, __shfl_xor(mx, 32));  // row q=lo fully reduced
    float mnew = fmaxf(m_, mx);
    float alpha = EXP2F(m_ - mnew);
    m_ = mnew;
    float rs = 0.f;
    half4 pf[4];
#pragma unroll
    for (int kvt = 0; kvt < 4; kvt++) {
      half4 p4;
#pragma unroll
      for (int r = 0; r < 4; r++) {
        float p = EXP2F(z[kvt][r] - mnew);
        p4[r] = (_Float16)p;
        rs += p;
      }
      pf[kvt] = p4;
    }
    rs += __shfl_xor(rs, 16);
    rs += __shfl_xor(rs, 32);
    l_ = l_ * alpha + rs;
    // alpha indexed by q=lo; oacc rows are q=quad*4+r -> broadcast transpose
    float ab[4];
#pragma unroll
    for (int r = 0; r < 4; r++) ab[r] = __shfl(alpha, (lane & 48) + quad * 4 + r);
#pragma unroll
    for (int ni = 0; ni < 4; ni++)
#pragma unroll
      for (int r = 0; r < 4; r++) oacc[ni][r] *= ab[r];

    // O += P @ V (K=16 f16 MFMA; P a-frags already in registers)
#pragma unroll
    for (int kvt = 0; kvt < 4; kvt++)
#pragma unroll
      for (int ni = 0; ni < 4; ni++) {
        half4 vf = *(const half4*)&vs[swz64(ni * 16 + lo, kvt * 16 + quad * 4)];
        oacc[ni] = __builtin_amdgcn_mfma_f32_16x16x16f16(pf[kvt], vf, oacc[ni], 0, 0, 0);
      }
  }

  float inv[4];
#pragma unroll
  for (int r = 0; r < 4; r++)
    inv[r] = 1.0f / __shfl(l_, (lane & 48) + quad * 4 + r);
#pragma unroll
  for (int ni = 0; ni < 4; ni++)
#pragma unroll
    for (int r = 0; r < 4; r++) {
      int qg = qrow0 + quad * 4 + r;
      O[base + (size_t)qg * DM + ni * 16 + lo] = f2bf(oacc[ni][r] * inv[r]);
    }
}

extern "C" void kernel_launch(void* const* d_in, const int* in_sizes, int n_in,
                              void* d_out, int out_size, void* d_ws, size_t ws_size,
                              hipStream_t stream) {
  const float* x  = (const float*)d_in[0];
  const float* Wq = (const float*)d_in[1];
  const float* Wk = (const float*)d_in[2];
  const float* Wv = (const float*)d_in[3];
  const float* Wo = (const float*)d_in[4];
  float* out = (float*)d_out;
  char* ws = (char*)d_ws;

  unsigned short* Xb  = (unsigned short*)(ws);
  unsigned short* Wqb = (unsigned short*)(ws + (8ll  << 20));
  unsigned short* Wkb = (unsigned short*)(ws + (10ll << 20));
  unsigned short* Wvb = (unsigned short*)(ws + (12ll << 20));
  unsigned short* Wob = (unsigned short*)(ws + (14ll << 20));
  unsigned short* Qb  = (unsigned short*)(ws + (16ll << 20));
  unsigned short* Kb  = (unsigned short*)(ws + (24ll << 20));
  _Float16*       Vt  = (_Float16*)     (ws + (32ll << 20));
  unsigned short* Ob  = (unsigned short*)(ws + (40ll << 20));

  cast5_kernel<<<dim3(4096, 5), 256, 0, stream>>>(x, Wq, Wk, Wv, Wo,
                                                  Xb, Wqb, Wkb, Wvb, Wob);
  gemm_qkv_kernel<<<dim3(32, 24), 256, 0, stream>>>(Xb, Wqb, Wkb, Wvb, Qb, Kb, Vt);
  attn_kernel<<<1024, 256, 0, stream>>>(Qb, Kb, Vt, Ob);
  gemm_out_kernel<<<dim3(32, 16), 256, 0, stream>>>(Ob, Wob, out);
}

// Round 4
// 187.655 us; speedup vs baseline: 1.7945x; 1.0295x over previous
//
#include <hip/hip_runtime.h>

// B=2, S=2048, D_MODEL=1024, H=16, Dh=64, M=B*S=4096.
// ws: Xb@0(8M) Wqb@8M Wkb@10M Wvb@12M Wob@14M (2M each, bf16)
//     Qb@16M(8M,bf16,pre-scaled by 1/8*log2e) Kb@24M(8M,bf16)
//     Vt@32M(8M,f16, layout [bh*64+d][2048]) Ob@40M(8M,bf16)

typedef __attribute__((ext_vector_type(8))) short short8;
typedef __attribute__((ext_vector_type(4))) float f32x4;
typedef __attribute__((ext_vector_type(4))) _Float16 half4;

#if __has_builtin(__builtin_amdgcn_exp2f)
#define EXP2F(x) __builtin_amdgcn_exp2f(x)
#else
#define EXP2F(x) exp2f(x)
#endif

__device__ __forceinline__ unsigned short f2bf(float f) {
  unsigned int x = __float_as_uint(f);
  x += 0x7fffu + ((x >> 16) & 1u);  // RNE
  return (unsigned short)(x >> 16);
}

__device__ __forceinline__ void gload16(const void* g, void* l) {
  __builtin_amdgcn_global_load_lds(
      (const __attribute__((address_space(1))) void*)g,
      (__attribute__((address_space(3))) void*)l, 16, 0, 0);
}

// swizzled LDS offset (2-byte units) for 64-element rows:
// physical 16B chunk = logical chunk ^ (row & 7)
__device__ __forceinline__ int swz64(int row, int sc) {
  return row * 64 + ((((sc >> 3) ^ (row & 7)) << 3) | (sc & 7));
}

// ---------------- fused cast (x, Wq*scale, Wk, Wv, Wo), flat grid -----------
__global__ void cast_kernel(const float* __restrict__ x, const float* __restrict__ wq,
                            const float* __restrict__ wk, const float* __restrict__ wv,
                            const float* __restrict__ wo,
                            unsigned short* __restrict__ xb, unsigned short* __restrict__ wqb,
                            unsigned short* __restrict__ wkb, unsigned short* __restrict__ wvb,
                            unsigned short* __restrict__ wob) {
  int id = blockIdx.x;
  const float* in; unsigned short* out; int blk; float sc = 1.f;
  if (id < 4096) { in = x; out = xb; blk = id; }
  else {
    int wsel = (id - 4096) >> 10;
    blk = (id - 4096) & 1023;
    switch (wsel) {
      case 0: in = wq; out = wqb; sc = 0.18033688011112042f; break;  // (1/8)*log2(e)
      case 1: in = wk; out = wkb; break;
      case 2: in = wv; out = wvb; break;
      default: in = wo; out = wob; break;
    }
  }
  int i = blk * 256 + threadIdx.x;
  float4 v = ((const float4*)in)[i];
  union { unsigned short u[4]; uint2 p; } o;
  o.u[0] = f2bf(v.x * sc); o.u[1] = f2bf(v.y * sc);
  o.u[2] = f2bf(v.z * sc); o.u[3] = f2bf(v.w * sc);
  ((uint2*)out)[i] = o.p;
}

// ---------------- fused QKV projection: C = X @ W^T; V written transposed ----
#define GK 1024

__global__ __launch_bounds__(256) void gemm_qkv_kernel(
    const unsigned short* __restrict__ X,
    const unsigned short* __restrict__ Wq,
    const unsigned short* __restrict__ Wk,
    const unsigned short* __restrict__ Wv,
    unsigned short* __restrict__ Qo,
    unsigned short* __restrict__ Ko,
    _Float16* __restrict__ Vt) {
  __shared__ unsigned short As[2][128 * 32];
  __shared__ unsigned short Bs[2][128 * 32];
  int mb = blockIdx.x;
  int nbT = blockIdx.y;
  int sel = nbT >> 3, nb = nbT & 7;
  const unsigned short* W = sel == 0 ? Wq : (sel == 1 ? Wk : Wv);

  int tid = threadIdx.x;
  int w = tid >> 6, l = tid & 63, quad = l >> 4, lo = l & 15;
  int wm = (w >> 1) * 64, wn = (w & 1) * 64;

  f32x4 acc[4][4];
#pragma unroll
  for (int i = 0; i < 4; i++)
#pragma unroll
    for (int j = 0; j < 4; j++) acc[i][j] = (f32x4){0.f, 0.f, 0.f, 0.f};

  // prologue: stage k-tile 0 into buf 0
#pragma unroll
  for (int i = 0; i < 2; i++) {
    int c = i * 256 + tid;
    gload16(X + (size_t)(mb * 128 + (c >> 2)) * GK + (c & 3) * 8, (char*)As[0] + c * 16);
    gload16(W + (size_t)(nb * 128 + (c >> 2)) * GK + (c & 3) * 8, (char*)Bs[0] + c * 16);
  }

  for (int kt = 0; kt < 32; kt++) {
    __syncthreads();  // drains prefetch for this tile; separates prev readers
    if (kt + 1 < 32) {
      int nb_ = (kt + 1) & 1, k0 = (kt + 1) * 32;
#pragma unroll
      for (int i = 0; i < 2; i++) {
        int c = i * 256 + tid;
        gload16(X + (size_t)(mb * 128 + (c >> 2)) * GK + k0 + (c & 3) * 8,
                (char*)As[nb_] + c * 16);
        gload16(W + (size_t)(nb * 128 + (c >> 2)) * GK + k0 + (c & 3) * 8,
                (char*)Bs[nb_] + c * 16);
      }
    }
    const unsigned short* as = As[kt & 1];
    const unsigned short* bs = Bs[kt & 1];
    short8 a[4], b[4];
#pragma unroll
    for (int mi = 0; mi < 4; mi++)
      a[mi] = *(const short8*)&as[(wm + mi * 16 + lo) * 32 + quad * 8];
#pragma unroll
    for (int ni = 0; ni < 4; ni++)
      b[ni] = *(const short8*)&bs[(wn + ni * 16 + lo) * 32 + quad * 8];
#pragma unroll
    for (int mi = 0; mi < 4; mi++)
#pragma unroll
      for (int ni = 0; ni < 4; ni++)
        acc[mi][ni] = __builtin_amdgcn_mfma_f32_16x16x32_bf16(a[mi], b[ni],
                                                              acc[mi][ni], 0, 0, 0);
  }
  if (sel == 2) {
    // V^T epilogue: Vt[(b*16+h)*64 + d][s], f16, 8B store of 4 consecutive s
#pragma unroll
    for (int mi = 0; mi < 4; mi++)
#pragma unroll
      for (int ni = 0; ni < 4; ni++) {
        int row0 = mb * 128 + wm + mi * 16 + quad * 4;
        int col = nb * 128 + wn + ni * 16 + lo;
        int bb = row0 >> 11, ss = row0 & 2047;
        int hh = col >> 6, dd = col & 63;
        half4 v;
#pragma unroll
        for (int r = 0; r < 4; r++) v[r] = (_Float16)acc[mi][ni][r];
        *(half4*)&Vt[((size_t)((bb * 16 + hh) * 64 + dd)) * 2048 + ss] = v;
      }
  } else {
    unsigned short* C = sel == 0 ? Qo : Ko;
#pragma unroll
    for (int mi = 0; mi < 4; mi++)
#pragma unroll
      for (int ni = 0; ni < 4; ni++)
#pragma unroll
        for (int r = 0; r < 4; r++) {
          int row = mb * 128 + wm + mi * 16 + quad * 4 + r;
          int col = nb * 128 + wn + ni * 16 + lo;
          C[(size_t)row * 1024 + col] = f2bf(acc[mi][ni][r]);
        }
  }
}

// ---------------- output projection: out(f32) = O @ Wo^T, 128x64 tiles ------
__global__ __launch_bounds__(256) void gemm_out_kernel(
    const unsigned short* __restrict__ A,
    const unsigned short* __restrict__ W,
    float* __restrict__ C) {
  __shared__ unsigned short As[2][128 * 32];
  __shared__ unsigned short Bs[2][64 * 32];
  int mb = blockIdx.x, nb = blockIdx.y;
  int tid = threadIdx.x;
  int w = tid >> 6, l = tid & 63, quad = l >> 4, lo = l & 15;
  int wm = w * 32;

  f32x4 acc[2][4];
#pragma unroll
  for (int i = 0; i < 2; i++)
#pragma unroll
    for (int j = 0; j < 4; j++) acc[i][j] = (f32x4){0.f, 0.f, 0.f, 0.f};

#pragma unroll
  for (int i = 0; i < 2; i++) {
    int c = i * 256 + tid;
    gload16(A + (size_t)(mb * 128 + (c >> 2)) * GK + (c & 3) * 8, (char*)As[0] + c * 16);
  }
  gload16(W + (size_t)(nb * 64 + (tid >> 2)) * GK + (tid & 3) * 8, (char*)Bs[0] + tid * 16);

  for (int kt = 0; kt < 32; kt++) {
    __syncthreads();
    if (kt + 1 < 32) {
      int nb_ = (kt + 1) & 1, k0 = (kt + 1) * 32;
#pragma unroll
      for (int i = 0; i < 2; i++) {
        int c = i * 256 + tid;
        gload16(A + (size_t)(mb * 128 + (c >> 2)) * GK + k0 + (c & 3) * 8,
                (char*)As[nb_] + c * 16);
      }
      gload16(W + (size_t)(nb * 64 + (tid >> 2)) * GK + k0 + (tid & 3) * 8,
              (char*)Bs[nb_] + tid * 16);
    }
    const unsigned short* as = As[kt & 1];
    const unsigned short* bs = Bs[kt & 1];
    short8 a[2], b[4];
#pragma unroll
    for (int mi = 0; mi < 2; mi++)
      a[mi] = *(const short8*)&as[(wm + mi * 16 + lo) * 32 + quad * 8];
#pragma unroll
    for (int ni = 0; ni < 4; ni++)
      b[ni] = *(const short8*)&bs[(ni * 16 + lo) * 32 + quad * 8];
#pragma unroll
    for (int mi = 0; mi < 2; mi++)
#pragma unroll
      for (int ni = 0; ni < 4; ni++)
        acc[mi][ni] = __builtin_amdgcn_mfma_f32_16x16x32_bf16(a[mi], b[ni],
                                                              acc[mi][ni], 0, 0, 0);
  }
#pragma unroll
  for (int mi = 0; mi < 2; mi++)
#pragma unroll
    for (int ni = 0; ni < 4; ni++)
#pragma unroll
      for (int r = 0; r < 4; r++) {
        int row = mb * 128 + wm + mi * 16 + quad * 4 + r;
        int col = nb * 64 + ni * 16 + lo;
        C[(size_t)row * 1024 + col] = acc[mi][ni][r];
      }
}

// ---------------- flash attention, causal -----------------------------------
// Block = (b,h) x PAIR of complementary 64-row q-tiles {l, 31-l}: every block
// runs exactly 33 tile-iters -> no intra-CU drain tail. S^T via 16x16x32 bf16
// (A=K, B=Q); P stays in registers (C-layout == A-frag of 16x16x16 f16).
// Row-sums l come from a ones-column PV MFMA (5th accumulator, C-layout).
__global__ __launch_bounds__(256) void attn_kernel(
    const unsigned short* __restrict__ Q,
    const unsigned short* __restrict__ K,
    const _Float16* __restrict__ Vt,
    unsigned short* __restrict__ O) {
  const int S = 2048, DM = 1024;
  __shared__ unsigned short Qs[64 * 64];
  __shared__ unsigned short Ks[2][64 * 64];
  __shared__ _Float16 Vts[2][64 * 64];

  int id = blockIdx.x;
  int bh = id & 31;
  int lsel = id >> 5;  // 0..15
  int b = bh >> 4, h = bh & 15;
  size_t base = (size_t)b * S * DM + h * 64;
  size_t baseVt = (size_t)(bh * 64) * S;

  int tid = threadIdx.x;
  int w = tid >> 6, lane = tid & 63, quad = lane >> 4, lo = lane & 15;
  const half4 ones = {(_Float16)1.f, (_Float16)1.f, (_Float16)1.f, (_Float16)1.f};

  for (int phase = 0; phase < 2; phase++) {
    int qt = phase ? (31 - lsel) : lsel;
    int qrow0 = qt * 64 + w * 16;
    __syncthreads();  // prev phase's LDS readers done before restaging buf 0

    // stage Q tile + K/V tile 0 into buf 0 (swizzled)
#pragma unroll
    for (int j = 0; j < 2; j++) {
      int s_ = j * 256 + tid;
      int row = s_ >> 3, lc = (s_ & 7) ^ (row & 7);
      gload16(Q + base + (size_t)(qt * 64 + row) * DM + lc * 8, (char*)Qs + s_ * 16);
      gload16(K + base + (size_t)row * DM + lc * 8, (char*)Ks[0] + s_ * 16);
      gload16(Vt + baseVt + (size_t)row * S + lc * 8, (char*)Vts[0] + s_ * 16);
    }

    short8 qf[2];
    f32x4 oacc[4], lacc;
    float m_ = -1e30f;
    lacc = (f32x4){0.f, 0.f, 0.f, 0.f};
#pragma unroll
    for (int ni = 0; ni < 4; ni++) oacc[ni] = (f32x4){0.f, 0.f, 0.f, 0.f};

    int tend = qt + 1;
    for (int t = 0; t < tend; t++) {
      __syncthreads();  // buf[t&1] (and Qs at t=0) ready for all waves
      if (t + 1 < tend) {
        int tb = (t + 1) & 1;
#pragma unroll
        for (int j = 0; j < 2; j++) {
          int s_ = j * 256 + tid;
          int row = s_ >> 3, lc = (s_ & 7) ^ (row & 7);
          gload16(K + base + (size_t)((t + 1) * 64 + row) * DM + lc * 8,
                  (char*)Ks[tb] + s_ * 16);
          gload16(Vt + baseVt + (size_t)row * S + (t + 1) * 64 + lc * 8,
                  (char*)Vts[tb] + s_ * 16);
        }
      }
      if (t == 0) {  // cache Q fragments in registers
#pragma unroll
        for (int d = 0; d < 2; d++)
          qf[d] = *(const short8*)&Qs[swz64(w * 16 + lo, d * 32 + quad * 8)];
      }
      const unsigned short* ks = Ks[t & 1];
      const _Float16* vs = Vts[t & 1];

      // S^T[kv][q]; Q pre-scaled -> log2-domain scores
      f32x4 st[4];
#pragma unroll
      for (int kvt = 0; kvt < 4; kvt++) st[kvt] = (f32x4){0.f, 0.f, 0.f, 0.f};
#pragma unroll
      for (int kvt = 0; kvt < 4; kvt++)
#pragma unroll
        for (int d = 0; d < 2; d++) {
          short8 kf = *(const short8*)&ks[swz64(kvt * 16 + lo, d * 32 + quad * 8)];
          st[kvt] = __builtin_amdgcn_mfma_f32_16x16x32_bf16(kf, qf[d], st[kvt], 0, 0, 0);
        }

      if (t == tend - 1) {  // diagonal tile: causal mask (in place)
        int qg = qrow0 + lo;
#pragma unroll
        for (int kvt = 0; kvt < 4; kvt++)
#pragma unroll
          for (int r = 0; r < 4; r++) {
            int kv = t * 64 + kvt * 16 + quad * 4 + r;
            if (kv > qg) st[kvt][r] = -1e30f;
          }
      }

      float mx = st[0][0];
#pragma unroll
      for (int kvt = 0; kvt < 4; kvt++)
#pragma unroll
        for (int r = 0; r < 4; r++) mx = fmaxf(mx, st[kvt][r]);
      mx = fmaxf(mx, __shfl_xor(mx, 16));
      mx = fmaxf(mx, __shfl_xor(mx, 32));  // row q=lo fully reduced
      float mnew = fmaxf(m_, mx);
      float alpha = EXP2F(m_ - mnew);
      m_ = mnew;
      half4 pf[4];
#pragma unroll
      for (int kvt = 0; kvt < 4; kvt++) {
        half4 p4;
#pragma unroll
        for (int r = 0; r < 4; r++) p4[r] = (_Float16)EXP2F(st[kvt][r] - mnew);
        pf[kvt] = p4;
      }
      // alpha indexed by q=lo; acc rows are q=quad*4+r -> broadcast transpose
      float ab[4];
#pragma unroll
      for (int r = 0; r < 4; r++) ab[r] = __shfl(alpha, (lane & 48) + quad * 4 + r);
#pragma unroll
      for (int ni = 0; ni < 4; ni++)
#pragma unroll
        for (int r = 0; r < 4; r++) oacc[ni][r] *= ab[r];
#pragma unroll
      for (int r = 0; r < 4; r++) lacc[r] *= ab[r];

      // O += P @ V; l += P @ 1 (K=16 f16 MFMA; P a-frags already in registers)
#pragma unroll
      for (int kvt = 0; kvt < 4; kvt++) {
#pragma unroll
        for (int ni = 0; ni < 4; ni++) {
          half4 vf = *(const half4*)&vs[swz64(ni * 16 + lo, kvt * 16 + quad * 4)];
          oacc[ni] = __builtin_amdgcn_mfma_f32_16x16x16f16(pf[kvt], vf, oacc[ni], 0, 0, 0);
        }
        lacc = __builtin_amdgcn_mfma_f32_16x16x16f16(pf[kvt], ones, lacc, 0, 0, 0);
      }
    }

    float inv[4];
#pragma unroll
    for (int r = 0; r < 4; r++) inv[r] = 1.0f / lacc[r];
#pragma unroll
    for (int ni = 0; ni < 4; ni++)
#pragma unroll
      for (int r = 0; r < 4; r++) {
        int qg = qrow0 + quad * 4 + r;
        O[base + (size_t)qg * DM + ni * 16 + lo] = f2bf(oacc[ni][r] * inv[r]);
      }
  }
}

extern "C" void kernel_launch(void* const* d_in, const int* in_sizes, int n_in,
                              void* d_out, int out_size, void* d_ws, size_t ws_size,
                              hipStream_t stream) {
  const float* x  = (const float*)d_in[0];
  const float* Wq = (const float*)d_in[1];
  const float* Wk = (const float*)d_in[2];
  const float* Wv = (const float*)d_in[3];
  const float* Wo = (const float*)d_in[4];
  float* out = (float*)d_out;
  char* ws = (char*)d_ws;

  unsigned short* Xb  = (unsigned short*)(ws);
  unsigned short* Wqb = (unsigned short*)(ws + (8ll  << 20));
  unsigned short* Wkb = (unsigned short*)(ws + (10ll << 20));
  unsigned short* Wvb = (unsigned short*)(ws + (12ll << 20));
  unsigned short* Wob = (unsigned short*)(ws + (14ll << 20));
  unsigned short* Qb  = (unsigned short*)(ws + (16ll << 20));
  unsigned short* Kb  = (unsigned short*)(ws + (24ll << 20));
  _Float16*       Vt  = (_Float16*)     (ws + (32ll << 20));
  unsigned short* Ob  = (unsigned short*)(ws + (40ll << 20));

  cast_kernel<<<8192, 256, 0, stream>>>(x, Wq, Wk, Wv, Wo, Xb, Wqb, Wkb, Wvb, Wob);
  gemm_qkv_kernel<<<dim3(32, 24), 256, 0, stream>>>(Xb, Wqb, Wkb, Wvb, Qb, Kb, Vt);
  attn_kernel<<<512, 256, 0, stream>>>(Qb, Kb, Vt, Ob);
  gemm_out_kernel<<<dim3(32, 16), 256, 0, stream>>>(Ob, Wob, out);
}